// Round 1
// baseline (198.852 us; speedup 1.0000x reference)
//
#include <hip/hip_runtime.h>
#include <cmath>

// NSAB_5420248727612: per-row sigmoid-moment reductions + 2x2 Newton solve.
// B=2048 rows, N=8192 cols fp32. Memory-bound: 64 MiB read of x.
// One 256-thread block per row. KEY CHANGE vs prior version: 4 clustered
// float4 loads per thread per iteration (4 KB in flight per wave) to fix
// the MLP/latency limit that held the kernel at ~50% of HBM BW.
// __launch_bounds__(256,6): cap VGPRs so >=24 waves/CU (6/SIMD) resident.

#define THREADS 256

__device__ __forceinline__ float fast_exp2(float t) {
#if __has_builtin(__builtin_amdgcn_exp2f)
    return __builtin_amdgcn_exp2f(t);   // v_exp_f32
#else
    return exp2f(t);
#endif
}

__device__ __forceinline__ float fast_rcp(float t) {
#if __has_builtin(__builtin_amdgcn_rcpf)
    return __builtin_amdgcn_rcpf(t);    // v_rcp_f32 (~1 ulp)
#else
    return 1.0f / t;
#endif
}

__global__ __launch_bounds__(THREADS, 6) void nsab_kernel(
    const float* __restrict__ x,
    const float* __restrict__ a,
    const float* __restrict__ b,
    const float* __restrict__ meanp,
    const float* __restrict__ varp,
    float* __restrict__ out,
    int B, int N)
{
    const int row = blockIdx.x;
    const int tid = threadIdx.x;

    const float av = a[row];
    const float bv = b[row];
    // s = 1/(1+exp(-(a*x+b))) = 1/(1+exp2(c1*x+c0)), c1=-a*log2(e), c0=-b*log2(e)
    const float LOG2E = 1.4426950408889634f;
    const float c1 = -av * LOG2E;
    const float c0 = -bv * LOG2E;

    const float4* __restrict__ xr = (const float4*)(x + (size_t)row * (size_t)N);
    const int nvec = N >> 2;

    // 12 row sums (same quantities as before):
    //  s, s^2, sp, sp*x, spp, spp*x, spp*x^2, s*sp, s*sp*x, w, w*x, w*x^2
    //  where sp=s(1-s), spp=sp(1-2s), w=sp^2+s*spp
    float a_s = 0.f, a_ss = 0.f, a_sp = 0.f, a_spx = 0.f;
    float a_q = 0.f, a_qx = 0.f, a_qx2 = 0.f;
    float a_fsp = 0.f, a_fspx = 0.f;
    float a_w = 0.f, a_wx = 0.f, a_wx2 = 0.f;

    // per-element update (VALU-trimmed):
    //   sp  = fmaf(-s, s, s)          (1 op, was sub+mul)
    //   ssp = s*sp
    //   spp = fmaf(-2, ssp, sp)       (reuses ssp; 1 op)
    #define NSAB_PROC(xx_)  do {                                        \
        const float xx  = (xx_);                                        \
        const float e   = fast_exp2(fmaf(c1, xx, c0));                  \
        const float s   = fast_rcp(1.0f + e);                           \
        const float sp  = fmaf(-s, s, s);                               \
        const float ssp = s * sp;                                       \
        const float spp = fmaf(-2.0f, ssp, sp);                         \
        const float w   = fmaf(s, spp, sp * sp);                        \
        const float x2  = xx * xx;                                      \
        a_s   += s;                                                     \
        a_ss   = fmaf(s,   s,   a_ss);                                  \
        a_sp  += sp;                                                    \
        a_spx  = fmaf(sp,  xx,  a_spx);                                 \
        a_q   += spp;                                                   \
        a_qx   = fmaf(spp, xx,  a_qx);                                  \
        a_qx2  = fmaf(spp, x2,  a_qx2);                                 \
        a_fsp += ssp;                                                   \
        a_fspx = fmaf(ssp, xx,  a_fspx);                                \
        a_w   += w;                                                     \
        a_wx   = fmaf(w,   xx,  a_wx);                                  \
        a_wx2  = fmaf(w,   x2,  a_wx2);                                 \
    } while (0)

    int i = tid;
    // Main path: 4 clustered float4 loads -> 4 KB in flight per wave.
    // For N=8192: nvec=2048, exactly 2 batches per thread, no remainder.
    for (; i + 3 * THREADS < nvec; i += 4 * THREADS) {
        float4 v0 = xr[i];
        float4 v1 = xr[i +     THREADS];
        float4 v2 = xr[i + 2 * THREADS];
        float4 v3 = xr[i + 3 * THREADS];
        NSAB_PROC(v0.x); NSAB_PROC(v0.y); NSAB_PROC(v0.z); NSAB_PROC(v0.w);
        NSAB_PROC(v1.x); NSAB_PROC(v1.y); NSAB_PROC(v1.z); NSAB_PROC(v1.w);
        NSAB_PROC(v2.x); NSAB_PROC(v2.y); NSAB_PROC(v2.z); NSAB_PROC(v2.w);
        NSAB_PROC(v3.x); NSAB_PROC(v3.y); NSAB_PROC(v3.z); NSAB_PROC(v3.w);
    }
    // Remainder (not taken for N=8192, kept for generality).
    for (; i < nvec; i += THREADS) {
        float4 v = xr[i];
        NSAB_PROC(v.x); NSAB_PROC(v.y); NSAB_PROC(v.z); NSAB_PROC(v.w);
    }
    #undef NSAB_PROC

    float acc[12] = {a_s, a_ss, a_sp, a_spx, a_q, a_qx, a_qx2,
                     a_fsp, a_fspx, a_w, a_wx, a_wx2};

    // 64-lane wave butterfly reduce
    #pragma unroll
    for (int k = 0; k < 12; ++k) {
        float v = acc[k];
        #pragma unroll
        for (int off = 32; off > 0; off >>= 1)
            v += __shfl_down(v, off, 64);
        acc[k] = v;
    }

    __shared__ float part[THREADS / 64][12];
    const int wave = tid >> 6;
    const int lane = tid & 63;
    if (lane == 0) {
        #pragma unroll
        for (int k = 0; k < 12; ++k) part[wave][k] = acc[k];
    }
    __syncthreads();

    if (tid == 0) {
        double S[12];
        #pragma unroll
        for (int k = 0; k < 12; ++k)
            S[k] = (double)part[0][k] + (double)part[1][k]
                 + (double)part[2][k] + (double)part[3][k];

        const double invN = 1.0 / (double)N;
        const double fm       = S[0]  * invN;
        const double mff      = S[1]  * invN;
        const double dem_db   = S[2]  * invN;
        const double dem_da   = S[3]  * invN;
        const double d2em_db2 = S[4]  * invN;
        const double d2em_dab = S[5]  * invN;
        const double d2em_da2 = S[6]  * invN;
        const double m_fdfb   = S[7]  * invN;
        const double m_fdfa   = S[8]  * invN;
        const double m_w      = S[9]  * invN;
        const double m_wx     = S[10] * invN;
        const double m_wx2    = S[11] * invN;

        const double mv = (double)meanp[row];
        const double vv = (double)varp[row];

        const double em = fm - mv;
        const double ev = mff - fm * fm - vv;
        const double dev_da = 2.0 * (m_fdfa - fm * dem_da);
        const double dev_db = 2.0 * (m_fdfb - fm * dem_db);
        const double d2ev_da2 = 2.0 * (m_wx2 - dem_da * dem_da - fm * d2em_da2);
        const double d2ev_dab = 2.0 * (m_wx  - dem_da * dem_db - fm * d2em_dab);
        const double d2ev_db2 = 2.0 * (m_w   - dem_db * dem_db - fm * d2em_db2);

        const double dl_da = 2.0 * (em * dem_da + ev * dev_da);
        const double dl_db = 2.0 * (em * dem_db + ev * dev_db);
        const double d2l_da2 = 2.0 * (dem_da * dem_da + em * d2em_da2
                                    + dev_da * dev_da + ev * d2ev_da2);
        const double d2l_dab = 2.0 * (dem_da * dem_db + em * d2em_dab
                                    + dev_da * dev_db + ev * d2ev_dab);
        const double d2l_db2 = 2.0 * (dem_db * dem_db + em * d2em_db2
                                    + dev_db * dev_db + ev * d2ev_db2);

        const double den = d2l_da2 * d2l_db2 - d2l_dab * d2l_dab;
        const double na = (dl_da * d2l_db2 - dl_db * d2l_dab) / den;
        const double nb = (dl_db * d2l_da2 - dl_da * d2l_dab) / den;

        out[row]     = (float)na;
        out[B + row] = (float)nb;
    }
}

extern "C" void kernel_launch(void* const* d_in, const int* in_sizes, int n_in,
                              void* d_out, int out_size, void* d_ws, size_t ws_size,
                              hipStream_t stream) {
    const float* x    = (const float*)d_in[0];
    const float* a    = (const float*)d_in[1];
    const float* b    = (const float*)d_in[2];
    const float* mean = (const float*)d_in[3];
    const float* var  = (const float*)d_in[4];
    const int B = in_sizes[1];            // a is (B,1)
    const int N = in_sizes[0] / B;        // x is (B,N)
    float* out = (float*)d_out;

    nsab_kernel<<<dim3(B), dim3(THREADS), 0, stream>>>(x, a, b, mean, var, out, B, N);
}

// Round 2
// 107.599 us; speedup vs baseline: 1.8481x; 1.8481x over previous
//
#include <hip/hip_runtime.h>
#include <cmath>

// NSAB_5420248727612: per-row sigmoid-moment reductions + 2x2 Newton solve.
// B=2048 rows, N=8192 cols fp32. Memory-bound: 64 MiB read of x.
// One 256-thread block per row; 4 clustered float4 loads per thread per
// iteration (4 KB in flight per wave) for memory-level parallelism.
// NOTE (round-1 post-mortem): __launch_bounds__(256,6) capped VGPRs at 40
// -> accumulators spilled to scratch (236 MiB WRITE_SIZE, 5x slowdown).
// Do NOT set the min-waves arg here; the live set is ~70+ VGPRs.
// Math kept in round-0 form: absmax was 7.6e-6; fmaf re-association of
// sp/spp fed the cancellation-prone Newton solve and cost 2 digits.

#define THREADS 256

__device__ __forceinline__ float fast_exp2(float t) {
#if __has_builtin(__builtin_amdgcn_exp2f)
    return __builtin_amdgcn_exp2f(t);   // v_exp_f32
#else
    return exp2f(t);
#endif
}

__device__ __forceinline__ float fast_rcp(float t) {
#if __has_builtin(__builtin_amdgcn_rcpf)
    return __builtin_amdgcn_rcpf(t);    // v_rcp_f32 (~1 ulp)
#else
    return 1.0f / t;
#endif
}

__global__ __launch_bounds__(THREADS) void nsab_kernel(
    const float* __restrict__ x,
    const float* __restrict__ a,
    const float* __restrict__ b,
    const float* __restrict__ meanp,
    const float* __restrict__ varp,
    float* __restrict__ out,
    int B, int N)
{
    const int row = blockIdx.x;
    const int tid = threadIdx.x;

    const float av = a[row];
    const float bv = b[row];
    // s = 1/(1+exp(-(a*x+b))) = 1/(1+exp2(c1*x+c0)), c1=-a*log2(e), c0=-b*log2(e)
    const float LOG2E = 1.4426950408889634f;
    const float c1 = -av * LOG2E;
    const float c0 = -bv * LOG2E;

    const float4* __restrict__ xr = (const float4*)(x + (size_t)row * (size_t)N);
    const int nvec = N >> 2;

    // 12 row sums:
    //  s, s^2, sp, sp*x, spp, spp*x, spp*x^2, s*sp, s*sp*x, w, w*x, w*x^2
    //  where sp=s(1-s), spp=sp(1-2s), w=sp^2+s*spp
    float a_s = 0.f, a_ss = 0.f, a_sp = 0.f, a_spx = 0.f;
    float a_q = 0.f, a_qx = 0.f, a_qx2 = 0.f;
    float a_fsp = 0.f, a_fspx = 0.f;
    float a_w = 0.f, a_wx = 0.f, a_wx2 = 0.f;

    // Round-0 math (accuracy-validated: absmax 7.6e-6).
    #define NSAB_PROC(xx_)  do {                                        \
        const float xx  = (xx_);                                        \
        const float e   = fast_exp2(fmaf(c1, xx, c0));                  \
        const float s   = fast_rcp(1.0f + e);                           \
        const float sp  = s * (1.0f - s);                               \
        const float spp = sp * fmaf(-2.0f, s, 1.0f);                    \
        const float ssp = s * sp;                                       \
        const float w   = fmaf(s, spp, sp * sp);                        \
        const float x2  = xx * xx;                                      \
        a_s   += s;                                                     \
        a_ss   = fmaf(s,   s,   a_ss);                                  \
        a_sp  += sp;                                                    \
        a_spx  = fmaf(sp,  xx,  a_spx);                                 \
        a_q   += spp;                                                   \
        a_qx   = fmaf(spp, xx,  a_qx);                                  \
        a_qx2  = fmaf(spp, x2,  a_qx2);                                 \
        a_fsp += ssp;                                                   \
        a_fspx = fmaf(ssp, xx,  a_fspx);                                \
        a_w   += w;                                                     \
        a_wx   = fmaf(w,   xx,  a_wx);                                  \
        a_wx2  = fmaf(w,   x2,  a_wx2);                                 \
    } while (0)

    int i = tid;
    // Main path: 4 clustered float4 loads -> 4 KB in flight per wave.
    // For N=8192: nvec=2048, exactly 2 batches per thread, no remainder.
    for (; i + 3 * THREADS < nvec; i += 4 * THREADS) {
        float4 v0 = xr[i];
        float4 v1 = xr[i +     THREADS];
        float4 v2 = xr[i + 2 * THREADS];
        float4 v3 = xr[i + 3 * THREADS];
        NSAB_PROC(v0.x); NSAB_PROC(v0.y); NSAB_PROC(v0.z); NSAB_PROC(v0.w);
        NSAB_PROC(v1.x); NSAB_PROC(v1.y); NSAB_PROC(v1.z); NSAB_PROC(v1.w);
        NSAB_PROC(v2.x); NSAB_PROC(v2.y); NSAB_PROC(v2.z); NSAB_PROC(v2.w);
        NSAB_PROC(v3.x); NSAB_PROC(v3.y); NSAB_PROC(v3.z); NSAB_PROC(v3.w);
    }
    // Remainder (not taken for N=8192, kept for generality).
    for (; i < nvec; i += THREADS) {
        float4 v = xr[i];
        NSAB_PROC(v.x); NSAB_PROC(v.y); NSAB_PROC(v.z); NSAB_PROC(v.w);
    }
    #undef NSAB_PROC

    float acc[12] = {a_s, a_ss, a_sp, a_spx, a_q, a_qx, a_qx2,
                     a_fsp, a_fspx, a_w, a_wx, a_wx2};

    // 64-lane wave butterfly reduce
    #pragma unroll
    for (int k = 0; k < 12; ++k) {
        float v = acc[k];
        #pragma unroll
        for (int off = 32; off > 0; off >>= 1)
            v += __shfl_down(v, off, 64);
        acc[k] = v;
    }

    __shared__ float part[THREADS / 64][12];
    const int wave = tid >> 6;
    const int lane = tid & 63;
    if (lane == 0) {
        #pragma unroll
        for (int k = 0; k < 12; ++k) part[wave][k] = acc[k];
    }
    __syncthreads();

    if (tid == 0) {
        double S[12];
        #pragma unroll
        for (int k = 0; k < 12; ++k)
            S[k] = (double)part[0][k] + (double)part[1][k]
                 + (double)part[2][k] + (double)part[3][k];

        const double invN = 1.0 / (double)N;
        const double fm       = S[0]  * invN;
        const double mff      = S[1]  * invN;
        const double dem_db   = S[2]  * invN;
        const double dem_da   = S[3]  * invN;
        const double d2em_db2 = S[4]  * invN;
        const double d2em_dab = S[5]  * invN;
        const double d2em_da2 = S[6]  * invN;
        const double m_fdfb   = S[7]  * invN;
        const double m_fdfa   = S[8]  * invN;
        const double m_w      = S[9]  * invN;
        const double m_wx     = S[10] * invN;
        const double m_wx2    = S[11] * invN;

        const double mv = (double)meanp[row];
        const double vv = (double)varp[row];

        const double em = fm - mv;
        const double ev = mff - fm * fm - vv;
        const double dev_da = 2.0 * (m_fdfa - fm * dem_da);
        const double dev_db = 2.0 * (m_fdfb - fm * dem_db);
        const double d2ev_da2 = 2.0 * (m_wx2 - dem_da * dem_da - fm * d2em_da2);
        const double d2ev_dab = 2.0 * (m_wx  - dem_da * dem_db - fm * d2em_dab);
        const double d2ev_db2 = 2.0 * (m_w   - dem_db * dem_db - fm * d2em_db2);

        const double dl_da = 2.0 * (em * dem_da + ev * dev_da);
        const double dl_db = 2.0 * (em * dem_db + ev * dev_db);
        const double d2l_da2 = 2.0 * (dem_da * dem_da + em * d2em_da2
                                    + dev_da * dev_da + ev * d2ev_da2);
        const double d2l_dab = 2.0 * (dem_da * dem_db + em * d2em_dab
                                    + dev_da * dev_db + ev * d2ev_dab);
        const double d2l_db2 = 2.0 * (dem_db * dem_db + em * d2em_db2
                                    + dev_db * dev_db + ev * d2ev_db2);

        const double den = d2l_da2 * d2l_db2 - d2l_dab * d2l_dab;
        const double na = (dl_da * d2l_db2 - dl_db * d2l_dab) / den;
        const double nb = (dl_db * d2l_da2 - dl_da * d2l_dab) / den;

        out[row]     = (float)na;
        out[B + row] = (float)nb;
    }
}

extern "C" void kernel_launch(void* const* d_in, const int* in_sizes, int n_in,
                              void* d_out, int out_size, void* d_ws, size_t ws_size,
                              hipStream_t stream) {
    const float* x    = (const float*)d_in[0];
    const float* a    = (const float*)d_in[1];
    const float* b    = (const float*)d_in[2];
    const float* mean = (const float*)d_in[3];
    const float* var  = (const float*)d_in[4];
    const int B = in_sizes[1];            // a is (B,1)
    const int N = in_sizes[0] / B;        // x is (B,N)
    float* out = (float*)d_out;

    nsab_kernel<<<dim3(B), dim3(THREADS), 0, stream>>>(x, a, b, mean, var, out, B, N);
}

// Round 3
// 104.184 us; speedup vs baseline: 1.9087x; 1.0328x over previous
//
#include <hip/hip_runtime.h>
#include <cmath>

// NSAB_5420248727612: per-row sigmoid-moment reductions + 2x2 Newton solve.
// B=2048 rows, N=8192 cols fp32. Memory-bound: 64 MiB read; floor ~10.7 us.
//
// Round-3 structure (post-mortems of r1/r2):
//  * r1: __launch_bounds__(256,6) -> 40-VGPR cap -> accumulator spills
//    (236 MiB scratch WRITE). NEVER set the min-waves arg here.
//  * r2: 4x clustered float4 loads pushed VGPR past the 64-reg occupancy
//    step (8 -> 4 waves/SIMD); kernel got SLOWER (21.7 -> 25.6 us).
//    Lesson: buy MLP and occupancy together, under 64 VGPR.
//  * r3: monomial accumulators. Every tracked quantity is a polynomial in
//    s of degree <=4 times {1, x, x^2}:
//      sp  = s - s^2
//      spp = s - 3 s^2 + 2 s^3
//      s*sp= s^2 - s^3
//      w   = sp^2 + s*spp = 2 s^2 - 5 s^3 + 3 s^4
//    So accumulate Sum s^k * {1, x, x^2}, k=1..4 (12 sums, 18 VALU + 2
//    trans per element, small live set), and reconstruct the original
//    means exactly in the f64 epilogue.
//  * 1-ahead software-pipelined float4 load; #pragma unroll 1 pins the
//    live set so VGPR stays <= 64 -> 8 waves/SIMD -> 32 KB/CU in flight.

#define THREADS 256

__device__ __forceinline__ float fast_exp2(float t) {
#if __has_builtin(__builtin_amdgcn_exp2f)
    return __builtin_amdgcn_exp2f(t);   // v_exp_f32
#else
    return exp2f(t);
#endif
}

__device__ __forceinline__ float fast_rcp(float t) {
#if __has_builtin(__builtin_amdgcn_rcpf)
    return __builtin_amdgcn_rcpf(t);    // v_rcp_f32 (~1 ulp)
#else
    return 1.0f / t;
#endif
}

__global__ __launch_bounds__(THREADS) void nsab_kernel(
    const float* __restrict__ x,
    const float* __restrict__ a,
    const float* __restrict__ b,
    const float* __restrict__ meanp,
    const float* __restrict__ varp,
    float* __restrict__ out,
    int B, int N)
{
    const int row = blockIdx.x;
    const int tid = threadIdx.x;

    const float av = a[row];
    const float bv = b[row];
    // s = 1/(1+exp(-(a*x+b))) = 1/(1+exp2(c1*x+c0))
    const float LOG2E = 1.4426950408889634f;
    const float c1 = -av * LOG2E;
    const float c0 = -bv * LOG2E;

    const float4* __restrict__ xr = (const float4*)(x + (size_t)row * (size_t)N);
    const int nvec = N >> 2;

    // 12 monomial sums: A_k = sum s^k, B_k = sum s^k x, C_k = sum s^k x^2
    float A1 = 0.f, A2 = 0.f, A3 = 0.f, A4 = 0.f;
    float B1 = 0.f, B2 = 0.f, B3 = 0.f, B4 = 0.f;
    float C1 = 0.f, C2 = 0.f, C3 = 0.f, C4 = 0.f;

    // 18 VALU + 2 transcendental per element.
    #define NSAB_PROC(xx_)  do {                                        \
        const float xx = (xx_);                                         \
        const float e  = fast_exp2(fmaf(c1, xx, c0));                   \
        const float s  = fast_rcp(1.0f + e);                            \
        const float s2 = s * s;                                         \
        const float s3 = s2 * s;                                        \
        const float s4 = s2 * s2;                                       \
        const float x2 = xx * xx;                                       \
        A1 += s;  A2 += s2;  A3 += s3;  A4 += s4;                       \
        B1 = fmaf(s,  xx, B1);  B2 = fmaf(s2, xx, B2);                  \
        B3 = fmaf(s3, xx, B3);  B4 = fmaf(s4, xx, B4);                  \
        C1 = fmaf(s,  x2, C1);  C2 = fmaf(s2, x2, C2);                  \
        C3 = fmaf(s3, x2, C3);  C4 = fmaf(s4, x2, C4);                  \
    } while (0)

    // 1-ahead software pipeline: one 1 KiB/wave load in flight while the
    // current float4 is processed. unroll 1 pins register pressure.
    int i = tid;
    if (i < nvec) {
        float4 cur = xr[i];
        #pragma unroll 1
        for (; i + THREADS < nvec; i += THREADS) {
            float4 nxt = xr[i + THREADS];
            NSAB_PROC(cur.x); NSAB_PROC(cur.y);
            NSAB_PROC(cur.z); NSAB_PROC(cur.w);
            cur = nxt;
        }
        NSAB_PROC(cur.x); NSAB_PROC(cur.y);
        NSAB_PROC(cur.z); NSAB_PROC(cur.w);
    }
    #undef NSAB_PROC

    float acc[12] = {A1, A2, A3, A4, B1, B2, B3, B4, C1, C2, C3, C4};

    // 64-lane wave butterfly reduce
    #pragma unroll
    for (int k = 0; k < 12; ++k) {
        float v = acc[k];
        #pragma unroll
        for (int off = 32; off > 0; off >>= 1)
            v += __shfl_down(v, off, 64);
        acc[k] = v;
    }

    __shared__ float part[THREADS / 64][12];
    const int wave = tid >> 6;
    const int lane = tid & 63;
    if (lane == 0) {
        #pragma unroll
        for (int k = 0; k < 12; ++k) part[wave][k] = acc[k];
    }
    __syncthreads();

    if (tid == 0) {
        double S[12];
        #pragma unroll
        for (int k = 0; k < 12; ++k)
            S[k] = (double)part[0][k] + (double)part[1][k]
                 + (double)part[2][k] + (double)part[3][k];

        const double invN = 1.0 / (double)N;
        const double M1 = S[0] * invN, M2 = S[1] * invN;
        const double M3 = S[2] * invN, M4 = S[3] * invN;
        const double X1 = S[4] * invN, X2 = S[5] * invN;
        const double X3 = S[6] * invN, X4 = S[7] * invN;
        const double Y1 = S[8] * invN, Y2 = S[9] * invN;
        const double Y3 = S[10] * invN, Y4 = S[11] * invN;

        // Exact reconstruction of the reference means:
        const double fm       = M1;
        const double mff      = M2;
        const double dem_db   = M1 - M2;                       // mean(sp)
        const double dem_da   = X1 - X2;                       // mean(sp x)
        const double d2em_db2 = M1 - 3.0 * M2 + 2.0 * M3;      // mean(spp)
        const double d2em_dab = X1 - 3.0 * X2 + 2.0 * X3;      // mean(spp x)
        const double d2em_da2 = Y1 - 3.0 * Y2 + 2.0 * Y3;      // mean(spp x^2)
        const double m_fdfb   = M2 - M3;                       // mean(s sp)
        const double m_fdfa   = X2 - X3;                       // mean(s sp x)
        const double m_w      = 2.0 * M2 - 5.0 * M3 + 3.0 * M4;   // mean(w)
        const double m_wx     = 2.0 * X2 - 5.0 * X3 + 3.0 * X4;   // mean(w x)
        const double m_wx2    = 2.0 * Y2 - 5.0 * Y3 + 3.0 * Y4;   // mean(w x^2)

        const double mv = (double)meanp[row];
        const double vv = (double)varp[row];

        const double em = fm - mv;
        const double ev = mff - fm * fm - vv;
        const double dev_da = 2.0 * (m_fdfa - fm * dem_da);
        const double dev_db = 2.0 * (m_fdfb - fm * dem_db);
        const double d2ev_da2 = 2.0 * (d2em_da2 >= 0 ? (m_wx2 - dem_da * dem_da - fm * d2em_da2)
                                                     : (m_wx2 - dem_da * dem_da - fm * d2em_da2));
        const double d2ev_dab = 2.0 * (m_wx  - dem_da * dem_db - fm * d2em_dab);
        const double d2ev_db2 = 2.0 * (m_w   - dem_db * dem_db - fm * d2em_db2);

        const double dl_da = 2.0 * (em * dem_da + ev * dev_da);
        const double dl_db = 2.0 * (em * dem_db + ev * dev_db);
        const double d2l_da2 = 2.0 * (dem_da * dem_da + em * d2em_da2
                                    + dev_da * dev_da + ev * d2ev_da2);
        const double d2l_dab = 2.0 * (dem_da * dem_db + em * d2em_dab
                                    + dev_da * dev_db + ev * d2ev_dab);
        const double d2l_db2 = 2.0 * (dem_db * dem_db + em * d2em_db2
                                    + dev_db * dev_db + ev * d2ev_db2);

        const double den = d2l_da2 * d2l_db2 - d2l_dab * d2l_dab;
        const double na = (dl_da * d2l_db2 - dl_db * d2l_dab) / den;
        const double nb = (dl_db * d2l_da2 - dl_da * d2l_dab) / den;

        out[row]     = (float)na;
        out[B + row] = (float)nb;
    }
}

extern "C" void kernel_launch(void* const* d_in, const int* in_sizes, int n_in,
                              void* d_out, int out_size, void* d_ws, size_t ws_size,
                              hipStream_t stream) {
    const float* x    = (const float*)d_in[0];
    const float* a    = (const float*)d_in[1];
    const float* b    = (const float*)d_in[2];
    const float* mean = (const float*)d_in[3];
    const float* var  = (const float*)d_in[4];
    const int B = in_sizes[1];            // a is (B,1)
    const int N = in_sizes[0] / B;        // x is (B,N)
    float* out = (float*)d_out;

    nsab_kernel<<<dim3(B), dim3(THREADS), 0, stream>>>(x, a, b, mean, var, out, B, N);
}

// Round 4
// 100.731 us; speedup vs baseline: 1.9741x; 1.0343x over previous
//
#include <hip/hip_runtime.h>
#include <cmath>

// NSAB_5420248727612: per-row sigmoid-moment reductions + 2x2 Newton solve.
// B=2048 rows, N=8192 cols fp32. Memory-bound: 64 MiB read; floor ~10.7 us.
//
// Round-4 structure (post-mortems r1-r3):
//  * r1: __launch_bounds__(256,6) -> 40-VGPR cap -> spills. Never cap.
//  * r2: 4-load cluster drained to 0 outstanding while processing 16 elems
//    (avg 1.5 loads in flight) -> no gain, regs up -> slower.
//  * r3: 18 VALU/elem + 1-ahead pipeline == r0 exactly (both ~22 us, 2.9
//    TB/s read vs fills' 6.5 TB/s write). Not VALU-bound, not 1-deep-fixable:
//    LATENCY-bound. Need outstanding-bytes >= BW*latency ~ 10-25 KB/CU.
//  * r4: full-depth MLP. Each thread owns exactly 8 float4 (N=8192): issue
//    all 8 independent loads back-to-back (8 KB outstanding PER WAVE), then
//    process in order (compiler emits incremental vmcnt waits). Even at 4
//    waves/SIMD -> 128 KB/CU in flight; occupancy cliff no longer matters.
//  * Monomial accumulators (sum s^k * {1,x,x^2}, k=1..4): 18 VALU + 2
//    trans/elem, exact f64 reconstruction in epilogue (absmax 1.5e-5).

#define THREADS 256

__device__ __forceinline__ float fast_exp2(float t) {
#if __has_builtin(__builtin_amdgcn_exp2f)
    return __builtin_amdgcn_exp2f(t);   // v_exp_f32
#else
    return exp2f(t);
#endif
}

__device__ __forceinline__ float fast_rcp(float t) {
#if __has_builtin(__builtin_amdgcn_rcpf)
    return __builtin_amdgcn_rcpf(t);    // v_rcp_f32 (~1 ulp)
#else
    return 1.0f / t;
#endif
}

__global__ __launch_bounds__(THREADS) void nsab_kernel(
    const float* __restrict__ x,
    const float* __restrict__ a,
    const float* __restrict__ b,
    const float* __restrict__ meanp,
    const float* __restrict__ varp,
    float* __restrict__ out,
    int B, int N)
{
    const int row = blockIdx.x;
    const int tid = threadIdx.x;

    const float av = a[row];
    const float bv = b[row];
    // s = 1/(1+exp(-(a*x+b))) = 1/(1+exp2(c1*x+c0))
    const float LOG2E = 1.4426950408889634f;
    const float c1 = -av * LOG2E;
    const float c0 = -bv * LOG2E;

    const float4* __restrict__ xr = (const float4*)(x + (size_t)row * (size_t)N);
    const int nvec = N >> 2;

    // 12 monomial sums: A_k = sum s^k, B_k = sum s^k x, C_k = sum s^k x^2
    float A1 = 0.f, A2 = 0.f, A3 = 0.f, A4 = 0.f;
    float B1 = 0.f, B2 = 0.f, B3 = 0.f, B4 = 0.f;
    float C1 = 0.f, C2 = 0.f, C3 = 0.f, C4 = 0.f;

    #define NSAB_PROC(xx_)  do {                                        \
        const float xx = (xx_);                                         \
        const float e  = fast_exp2(fmaf(c1, xx, c0));                   \
        const float s  = fast_rcp(1.0f + e);                            \
        const float s2 = s * s;                                         \
        const float s3 = s2 * s;                                        \
        const float s4 = s2 * s2;                                       \
        const float x2 = xx * xx;                                       \
        A1 += s;  A2 += s2;  A3 += s3;  A4 += s4;                       \
        B1 = fmaf(s,  xx, B1);  B2 = fmaf(s2, xx, B2);                  \
        B3 = fmaf(s3, xx, B3);  B4 = fmaf(s4, xx, B4);                  \
        C1 = fmaf(s,  x2, C1);  C2 = fmaf(s2, x2, C2);                  \
        C3 = fmaf(s3, x2, C3);  C4 = fmaf(s4, x2, C4);                  \
    } while (0)

    #define NSAB_PROC4(v)  do {                                         \
        NSAB_PROC((v).x); NSAB_PROC((v).y);                             \
        NSAB_PROC((v).z); NSAB_PROC((v).w);                             \
    } while (0)

    if (nvec == 8 * THREADS) {
        // Fast path (N=8192): 8 independent loads issued back-to-back;
        // 8 KB outstanding per wave; incremental vmcnt drain during compute.
        const float4* p = xr + tid;
        float4 v0 = p[0 * THREADS];
        float4 v1 = p[1 * THREADS];
        float4 v2 = p[2 * THREADS];
        float4 v3 = p[3 * THREADS];
        float4 v4 = p[4 * THREADS];
        float4 v5 = p[5 * THREADS];
        float4 v6 = p[6 * THREADS];
        float4 v7 = p[7 * THREADS];
        NSAB_PROC4(v0); NSAB_PROC4(v1); NSAB_PROC4(v2); NSAB_PROC4(v3);
        NSAB_PROC4(v4); NSAB_PROC4(v5); NSAB_PROC4(v6); NSAB_PROC4(v7);
    } else {
        // Generic fallback: 1-ahead pipeline (r3 structure).
        int i = tid;
        if (i < nvec) {
            float4 cur = xr[i];
            #pragma unroll 1
            for (; i + THREADS < nvec; i += THREADS) {
                float4 nxt = xr[i + THREADS];
                NSAB_PROC4(cur);
                cur = nxt;
            }
            NSAB_PROC4(cur);
        }
    }
    #undef NSAB_PROC4
    #undef NSAB_PROC

    float acc[12] = {A1, A2, A3, A4, B1, B2, B3, B4, C1, C2, C3, C4};

    // 64-lane wave butterfly reduce
    #pragma unroll
    for (int k = 0; k < 12; ++k) {
        float v = acc[k];
        #pragma unroll
        for (int off = 32; off > 0; off >>= 1)
            v += __shfl_down(v, off, 64);
        acc[k] = v;
    }

    __shared__ float part[THREADS / 64][12];
    const int wave = tid >> 6;
    const int lane = tid & 63;
    if (lane == 0) {
        #pragma unroll
        for (int k = 0; k < 12; ++k) part[wave][k] = acc[k];
    }
    __syncthreads();

    if (tid == 0) {
        double S[12];
        #pragma unroll
        for (int k = 0; k < 12; ++k)
            S[k] = (double)part[0][k] + (double)part[1][k]
                 + (double)part[2][k] + (double)part[3][k];

        const double invN = 1.0 / (double)N;
        const double M1 = S[0] * invN, M2 = S[1] * invN;
        const double M3 = S[2] * invN, M4 = S[3] * invN;
        const double X1 = S[4] * invN, X2 = S[5] * invN;
        const double X3 = S[6] * invN, X4 = S[7] * invN;
        const double Y1 = S[8] * invN, Y2 = S[9] * invN;
        const double Y3 = S[10] * invN, Y4 = S[11] * invN;

        // Exact reconstruction of the reference means:
        const double fm       = M1;
        const double mff      = M2;
        const double dem_db   = M1 - M2;                       // mean(sp)
        const double dem_da   = X1 - X2;                       // mean(sp x)
        const double d2em_db2 = M1 - 3.0 * M2 + 2.0 * M3;      // mean(spp)
        const double d2em_dab = X1 - 3.0 * X2 + 2.0 * X3;      // mean(spp x)
        const double d2em_da2 = Y1 - 3.0 * Y2 + 2.0 * Y3;      // mean(spp x^2)
        const double m_fdfb   = M2 - M3;                       // mean(s sp)
        const double m_fdfa   = X2 - X3;                       // mean(s sp x)
        const double m_w      = 2.0 * M2 - 5.0 * M3 + 3.0 * M4;   // mean(w)
        const double m_wx     = 2.0 * X2 - 5.0 * X3 + 3.0 * X4;   // mean(w x)
        const double m_wx2    = 2.0 * Y2 - 5.0 * Y3 + 3.0 * Y4;   // mean(w x^2)

        const double mv = (double)meanp[row];
        const double vv = (double)varp[row];

        const double em = fm - mv;
        const double ev = mff - fm * fm - vv;
        const double dev_da = 2.0 * (m_fdfa - fm * dem_da);
        const double dev_db = 2.0 * (m_fdfb - fm * dem_db);
        const double d2ev_da2 = 2.0 * (m_wx2 - dem_da * dem_da - fm * d2em_da2);
        const double d2ev_dab = 2.0 * (m_wx  - dem_da * dem_db - fm * d2em_dab);
        const double d2ev_db2 = 2.0 * (m_w   - dem_db * dem_db - fm * d2em_db2);

        const double dl_da = 2.0 * (em * dem_da + ev * dev_da);
        const double dl_db = 2.0 * (em * dem_db + ev * dev_db);
        const double d2l_da2 = 2.0 * (dem_da * dem_da + em * d2em_da2
                                    + dev_da * dev_da + ev * d2ev_da2);
        const double d2l_dab = 2.0 * (dem_da * dem_db + em * d2em_dab
                                    + dev_da * dev_db + ev * d2ev_dab);
        const double d2l_db2 = 2.0 * (dem_db * dem_db + em * d2em_db2
                                    + dev_db * dev_db + ev * d2ev_db2);

        const double den = d2l_da2 * d2l_db2 - d2l_dab * d2l_dab;
        const double na = (dl_da * d2l_db2 - dl_db * d2l_dab) / den;
        const double nb = (dl_db * d2l_da2 - dl_da * d2l_dab) / den;

        out[row]     = (float)na;
        out[B + row] = (float)nb;
    }
}

extern "C" void kernel_launch(void* const* d_in, const int* in_sizes, int n_in,
                              void* d_out, int out_size, void* d_ws, size_t ws_size,
                              hipStream_t stream) {
    const float* x    = (const float*)d_in[0];
    const float* a    = (const float*)d_in[1];
    const float* b    = (const float*)d_in[2];
    const float* mean = (const float*)d_in[3];
    const float* var  = (const float*)d_in[4];
    const int B = in_sizes[1];            // a is (B,1)
    const int N = in_sizes[0] / B;        // x is (B,N)
    float* out = (float*)d_out;

    nsab_kernel<<<dim3(B), dim3(THREADS), 0, stream>>>(x, a, b, mean, var, out, B, N);
}

// Round 5
// 100.705 us; speedup vs baseline: 1.9746x; 1.0003x over previous
//
#include <hip/hip_runtime.h>
#include <cmath>

// NSAB_5420248727612: per-row sigmoid-moment reductions + 2x2 Newton solve.
// B=2048 rows, N=8192 cols fp32. Memory-bound: 64 MiB read; floor ~10.7 us.
//
// Round-5 structure (post-mortems r1-r4):
//  * r1: __launch_bounds__(256,6) VGPR cap -> spills. Never cap.
//  * r2: clustered loads drained between clusters -> no gain.
//  * r3: VALU trim (22->18 ops/elem) changed nothing -> not VALU-bound.
//  * r4: 8-load burst per block: 22.2 -> 18.7 us. Helped but bursty:
//    all loads at block start, memory pipe idle during compute phase,
//    relaunch preamble between blocks. ~3.6 TB/s read.
//  * r5: ONE ROW PER WAVE + rolling 8-deep window. Named regs v0..v7;
//    steady loop processes v_k then reloads it from +8 ahead -> 8 KB/wave
//    outstanding SUSTAINED for the whole row. 512 blocks -> 8 waves/CU ->
//    64 KB/CU in flight continuously. No LDS, no __syncthreads: reduce is
//    wave-local shuffles; f64 solve per-wave on lane 0.
//  * Monomial accumulators (sum s^k * {1,x,x^2}, k=1..4): 18 VALU + 2
//    trans/elem; exact f64 reconstruction in epilogue (absmax ~1.5e-5).

#define THREADS 256

__device__ __forceinline__ float fast_exp2(float t) {
#if __has_builtin(__builtin_amdgcn_exp2f)
    return __builtin_amdgcn_exp2f(t);   // v_exp_f32
#else
    return exp2f(t);
#endif
}

__device__ __forceinline__ float fast_rcp(float t) {
#if __has_builtin(__builtin_amdgcn_rcpf)
    return __builtin_amdgcn_rcpf(t);    // v_rcp_f32 (~1 ulp)
#else
    return 1.0f / t;
#endif
}

// Shared f64 epilogue: S[12] are the 12 monomial ROW SUMS
// (A1..A4 = sum s^k, B1..B4 = sum s^k x, C1..C4 = sum s^k x^2).
__device__ __forceinline__ void nsab_epilogue(
    const double* S, int N, double mv, double vv,
    float* __restrict__ out, int B, int row)
{
    const double invN = 1.0 / (double)N;
    const double M1 = S[0] * invN, M2 = S[1] * invN;
    const double M3 = S[2] * invN, M4 = S[3] * invN;
    const double X1 = S[4] * invN, X2 = S[5] * invN;
    const double X3 = S[6] * invN, X4 = S[7] * invN;
    const double Y1 = S[8] * invN, Y2 = S[9] * invN;
    const double Y3 = S[10] * invN, Y4 = S[11] * invN;

    // Exact reconstruction of the reference means:
    const double fm       = M1;
    const double mff      = M2;
    const double dem_db   = M1 - M2;                        // mean(sp)
    const double dem_da   = X1 - X2;                        // mean(sp x)
    const double d2em_db2 = M1 - 3.0 * M2 + 2.0 * M3;       // mean(spp)
    const double d2em_dab = X1 - 3.0 * X2 + 2.0 * X3;       // mean(spp x)
    const double d2em_da2 = Y1 - 3.0 * Y2 + 2.0 * Y3;       // mean(spp x^2)
    const double m_fdfb   = M2 - M3;                        // mean(s sp)
    const double m_fdfa   = X2 - X3;                        // mean(s sp x)
    const double m_w      = 2.0 * M2 - 5.0 * M3 + 3.0 * M4; // mean(w)
    const double m_wx     = 2.0 * X2 - 5.0 * X3 + 3.0 * X4; // mean(w x)
    const double m_wx2    = 2.0 * Y2 - 5.0 * Y3 + 3.0 * Y4; // mean(w x^2)

    const double em = fm - mv;
    const double ev = mff - fm * fm - vv;
    const double dev_da = 2.0 * (m_fdfa - fm * dem_da);
    const double dev_db = 2.0 * (m_fdfb - fm * dem_db);
    const double d2ev_da2 = 2.0 * (m_wx2 - dem_da * dem_da - fm * d2em_da2);
    const double d2ev_dab = 2.0 * (m_wx  - dem_da * dem_db - fm * d2em_dab);
    const double d2ev_db2 = 2.0 * (m_w   - dem_db * dem_db - fm * d2em_db2);

    const double dl_da = 2.0 * (em * dem_da + ev * dev_da);
    const double dl_db = 2.0 * (em * dem_db + ev * dev_db);
    const double d2l_da2 = 2.0 * (dem_da * dem_da + em * d2em_da2
                                + dev_da * dev_da + ev * d2ev_da2);
    const double d2l_dab = 2.0 * (dem_da * dem_db + em * d2em_dab
                                + dev_da * dev_db + ev * d2ev_dab);
    const double d2l_db2 = 2.0 * (dem_db * dem_db + em * d2em_db2
                                + dev_db * dev_db + ev * d2ev_db2);

    const double den = d2l_da2 * d2l_db2 - d2l_dab * d2l_dab;
    const double na = (dl_da * d2l_db2 - dl_db * d2l_dab) / den;
    const double nb = (dl_db * d2l_da2 - dl_da * d2l_dab) / den;

    out[row]     = (float)na;
    out[B + row] = (float)nb;
}

// Per-element update: 18 VALU + 2 transcendental.
#define NSAB_PROC(xx_)  do {                                        \
    const float xx = (xx_);                                         \
    const float e  = fast_exp2(fmaf(c1, xx, c0));                   \
    const float s  = fast_rcp(1.0f + e);                            \
    const float s2 = s * s;                                         \
    const float s3 = s2 * s;                                        \
    const float s4 = s2 * s2;                                       \
    const float x2 = xx * xx;                                       \
    A1 += s;  A2 += s2;  A3 += s3;  A4 += s4;                       \
    B1 = fmaf(s,  xx, B1);  B2 = fmaf(s2, xx, B2);                  \
    B3 = fmaf(s3, xx, B3);  B4 = fmaf(s4, xx, B4);                  \
    C1 = fmaf(s,  x2, C1);  C2 = fmaf(s2, x2, C2);                  \
    C3 = fmaf(s3, x2, C3);  C4 = fmaf(s4, x2, C4);                  \
} while (0)

#define NSAB_PROC4(v)  do {                                         \
    NSAB_PROC((v).x); NSAB_PROC((v).y);                             \
    NSAB_PROC((v).z); NSAB_PROC((v).w);                             \
} while (0)

// Fast path: N == 8192, one row per wave, 4 rows per 256-thread block.
// Rolling 8-deep load window sustained across the whole row; no LDS,
// no __syncthreads.
__global__ __launch_bounds__(THREADS) void nsab_kernel_wpr(
    const float* __restrict__ x,
    const float* __restrict__ a,
    const float* __restrict__ b,
    const float* __restrict__ meanp,
    const float* __restrict__ varp,
    float* __restrict__ out,
    int B, int N)
{
    const int wave = threadIdx.x >> 6;
    const int lane = threadIdx.x & 63;
    const int row  = (blockIdx.x << 2) | wave;

    const float av = a[row];
    const float bv = b[row];
    const float LOG2E = 1.4426950408889634f;
    const float c1 = -av * LOG2E;
    const float c0 = -bv * LOG2E;

    // N=8192 -> nvec=2048 float4 -> 32 per lane at stride 64.
    const float4* __restrict__ p =
        (const float4*)(x + (size_t)row * (size_t)N) + lane;

    float A1 = 0.f, A2 = 0.f, A3 = 0.f, A4 = 0.f;
    float B1 = 0.f, B2 = 0.f, B3 = 0.f, B4 = 0.f;
    float C1 = 0.f, C2 = 0.f, C3 = 0.f, C4 = 0.f;

    // Prologue: fill the 8-deep window (named regs only -> no scratch).
    float4 v0 = p[0 * 64], v1 = p[1 * 64], v2 = p[2 * 64], v3 = p[3 * 64],
           v4 = p[4 * 64], v5 = p[5 * 64], v6 = p[6 * 64], v7 = p[7 * 64];

    // Steady state: process v_k, immediately reload it from +8 ahead.
    // 7-8 loads (8 KB/wave) outstanding continuously.
    #pragma unroll 1
    for (int g = 1; g < 4; ++g) {
        const float4* __restrict__ q = p + (size_t)g * 512;   // 8*64
        NSAB_PROC4(v0); v0 = q[0 * 64];
        NSAB_PROC4(v1); v1 = q[1 * 64];
        NSAB_PROC4(v2); v2 = q[2 * 64];
        NSAB_PROC4(v3); v3 = q[3 * 64];
        NSAB_PROC4(v4); v4 = q[4 * 64];
        NSAB_PROC4(v5); v5 = q[5 * 64];
        NSAB_PROC4(v6); v6 = q[6 * 64];
        NSAB_PROC4(v7); v7 = q[7 * 64];
    }
    // Epilogue: drain the window.
    NSAB_PROC4(v0); NSAB_PROC4(v1); NSAB_PROC4(v2); NSAB_PROC4(v3);
    NSAB_PROC4(v4); NSAB_PROC4(v5); NSAB_PROC4(v6); NSAB_PROC4(v7);

    float acc[12] = {A1, A2, A3, A4, B1, B2, B3, B4, C1, C2, C3, C4};

    // Wave-local butterfly reduce (full row lives in this wave).
    #pragma unroll
    for (int k = 0; k < 12; ++k) {
        float v = acc[k];
        #pragma unroll
        for (int off = 32; off > 0; off >>= 1)
            v += __shfl_down(v, off, 64);
        acc[k] = v;
    }

    if (lane == 0) {
        double S[12];
        #pragma unroll
        for (int k = 0; k < 12; ++k) S[k] = (double)acc[k];
        nsab_epilogue(S, N, (double)meanp[row], (double)varp[row], out, B, row);
    }
}

// Generic fallback (any B,N with N%4==0): round-4 block-per-row structure.
__global__ __launch_bounds__(THREADS) void nsab_kernel_generic(
    const float* __restrict__ x,
    const float* __restrict__ a,
    const float* __restrict__ b,
    const float* __restrict__ meanp,
    const float* __restrict__ varp,
    float* __restrict__ out,
    int B, int N)
{
    const int row = blockIdx.x;
    const int tid = threadIdx.x;

    const float av = a[row];
    const float bv = b[row];
    const float LOG2E = 1.4426950408889634f;
    const float c1 = -av * LOG2E;
    const float c0 = -bv * LOG2E;

    const float4* __restrict__ xr = (const float4*)(x + (size_t)row * (size_t)N);
    const int nvec = N >> 2;

    float A1 = 0.f, A2 = 0.f, A3 = 0.f, A4 = 0.f;
    float B1 = 0.f, B2 = 0.f, B3 = 0.f, B4 = 0.f;
    float C1 = 0.f, C2 = 0.f, C3 = 0.f, C4 = 0.f;

    int i = tid;
    if (i < nvec) {
        float4 cur = xr[i];
        #pragma unroll 1
        for (; i + THREADS < nvec; i += THREADS) {
            float4 nxt = xr[i + THREADS];
            NSAB_PROC4(cur);
            cur = nxt;
        }
        NSAB_PROC4(cur);
    }

    float acc[12] = {A1, A2, A3, A4, B1, B2, B3, B4, C1, C2, C3, C4};

    #pragma unroll
    for (int k = 0; k < 12; ++k) {
        float v = acc[k];
        #pragma unroll
        for (int off = 32; off > 0; off >>= 1)
            v += __shfl_down(v, off, 64);
        acc[k] = v;
    }

    __shared__ float part[THREADS / 64][12];
    const int wave = tid >> 6;
    const int lane = tid & 63;
    if (lane == 0) {
        #pragma unroll
        for (int k = 0; k < 12; ++k) part[wave][k] = acc[k];
    }
    __syncthreads();

    if (tid == 0) {
        double S[12];
        #pragma unroll
        for (int k = 0; k < 12; ++k)
            S[k] = (double)part[0][k] + (double)part[1][k]
                 + (double)part[2][k] + (double)part[3][k];
        nsab_epilogue(S, N, (double)meanp[row], (double)varp[row], out, B, row);
    }
}

extern "C" void kernel_launch(void* const* d_in, const int* in_sizes, int n_in,
                              void* d_out, int out_size, void* d_ws, size_t ws_size,
                              hipStream_t stream) {
    const float* x    = (const float*)d_in[0];
    const float* a    = (const float*)d_in[1];
    const float* b    = (const float*)d_in[2];
    const float* mean = (const float*)d_in[3];
    const float* var  = (const float*)d_in[4];
    const int B = in_sizes[1];            // a is (B,1)
    const int N = in_sizes[0] / B;        // x is (B,N)
    float* out = (float*)d_out;

    if (N == 8192 && (B & 3) == 0) {
        nsab_kernel_wpr<<<dim3(B >> 2), dim3(THREADS), 0, stream>>>(
            x, a, b, mean, var, out, B, N);
    } else {
        nsab_kernel_generic<<<dim3(B), dim3(THREADS), 0, stream>>>(
            x, a, b, mean, var, out, B, N);
    }
}